// Round 6
// baseline (706.826 us; speedup 1.0000x reference)
//
#include <hip/hip_runtime.h>
#include <math.h>

#define AUX_SLOTS 1024

// ---------------- vl: normalized V-projections, layout [R][H][L] ----------------
__global__ void vl_kernel(const float* __restrict__ llm, const float* __restrict__ Vw,
                          const float* __restrict__ Vb, float* __restrict__ vl) {
    int b = blockIdx.x;          // b = r*64 + l
    int r = b >> 6, l = b & 63;
    int t = threadIdx.x;         // h
    float acc = Vb[r * 64 + t];
    const float* w = Vw + (size_t)(r * 384) * 64 + t;
    const float* xr = llm + l * 384;
#pragma unroll 4
    for (int d = 0; d < 384; ++d) acc += xr[d] * w[(size_t)d * 64];
    float ss = acc * acc;
#pragma unroll
    for (int m = 1; m < 64; m <<= 1) ss += __shfl_xor(ss, m);
    float inv = 1.0f / fmaxf(sqrtf(ss), 1e-12f);
    vl[((size_t)r * 64 + t) * 64 + l] = acc * inv;   // [r][h][l]
}

// ---------------- gate: logits, top-2, aux partials, router counts ----------------
__global__ __launch_bounds__(256) void gate_kernel(
    const float* __restrict__ eh, const float* __restrict__ sr,
    const float* __restrict__ gw, const float* __restrict__ gb,
    int* __restrict__ rinfo, float* __restrict__ wbuf,
    float* __restrict__ aux, int* __restrict__ cnt, int N)
{
    __shared__ int lcnt[8];
    int tid = threadIdx.x;
    if (tid < 8) lcnt[tid] = 0;
    __syncthreads();
    int wave = tid >> 6, lane = tid & 63;
    int wgid = blockIdx.x * 4 + wave;
    float gbr[8];
#pragma unroll
    for (int r = 0; r < 8; ++r) gbr[r] = gb[r];
    float aux_acc = 0.f;

    for (int rr = 0; rr < 8; ++rr) {
        int row = wgid * 8 + rr;
        const float4* pa = (const float4*)(eh + (size_t)row * 384);
        const float4* pb = (const float4*)(sr + (size_t)row * 384);
        float4 xv0 = pa[lane];
        const float4* p1 = (lane < 32) ? (pa + 64 + lane) : (pb + (lane - 32));
        float4 xv1 = *p1;
        float4 xv2 = pb[lane + 32];

        float lg[8];
#pragma unroll
        for (int r = 0; r < 8; ++r) lg[r] = 0.f;
        {
            const float* g0 = gw + (size_t)lane * 32;
            const float* g1 = gw + (size_t)(lane + 64) * 32;
            const float* g2 = gw + (size_t)(lane + 128) * 32;
            float xd;
#pragma unroll
            for (int dd = 0; dd < 4; ++dd) {
                xd = (dd == 0) ? xv0.x : (dd == 1) ? xv0.y : (dd == 2) ? xv0.z : xv0.w;
#pragma unroll
                for (int r = 0; r < 8; ++r) lg[r] += xd * g0[dd * 8 + r];
            }
#pragma unroll
            for (int dd = 0; dd < 4; ++dd) {
                xd = (dd == 0) ? xv1.x : (dd == 1) ? xv1.y : (dd == 2) ? xv1.z : xv1.w;
#pragma unroll
                for (int r = 0; r < 8; ++r) lg[r] += xd * g1[dd * 8 + r];
            }
#pragma unroll
            for (int dd = 0; dd < 4; ++dd) {
                xd = (dd == 0) ? xv2.x : (dd == 1) ? xv2.y : (dd == 2) ? xv2.z : xv2.w;
#pragma unroll
                for (int r = 0; r < 8; ++r) lg[r] += xd * g2[dd * 8 + r];
            }
        }
#pragma unroll
        for (int m = 1; m < 64; m <<= 1) {
#pragma unroll
            for (int r = 0; r < 8; ++r) lg[r] += __shfl_xor(lg[r], m);
        }
#pragma unroll
        for (int r = 0; r < 8; ++r) lg[r] += gbr[r];

        float mx = lg[0];
#pragma unroll
        for (int r = 1; r < 8; ++r) mx = fmaxf(mx, lg[r]);
        float e8[8], se = 0.f;
#pragma unroll
        for (int r = 0; r < 8; ++r) { e8[r] = expf(lg[r] - mx); se += e8[r]; }

        int r0 = 0; float v0 = lg[0];
#pragma unroll
        for (int r = 1; r < 8; ++r) if (lg[r] > v0) { v0 = lg[r]; r0 = r; }
        int r1 = (r0 == 0) ? 1 : 0; float v1 = lg[r1];
#pragma unroll
        for (int r = 0; r < 8; ++r) if (r != r1 && r != r0 && lg[r] > v1) { v1 = lg[r]; r1 = r; }
        float z = expf(v1 - v0);
        float w0 = 1.f / (1.f + z), w1 = z / (1.f + z);

        if (lane == 0) {
            rinfo[row] = r0 | (r1 << 4);
            wbuf[2 * row] = w0; wbuf[2 * row + 1] = w1;
            atomicAdd(&lcnt[r0], 1);
            atomicAdd(&lcnt[r1], 1);
        }
#pragma unroll
        for (int r2 = 0; r2 < 8; ++r2) {
            if (lane == r2) aux_acc += e8[r2] / se;
            if (lane - 8 == r2) aux_acc += (r2 == r0 || r2 == r1) ? 1.f : 0.f;
        }
    }
    if (lane < 16) atomicAdd(aux + ((size_t)(wgid & (AUX_SLOTS - 1)) * 16) + lane, aux_acc);
    __syncthreads();
    if (tid < 8) atomicAdd(&cnt[tid], lcnt[tid]);
}

__global__ void prefix_kernel(const int* __restrict__ cnt, int* __restrict__ cur,
                              int* __restrict__ off) {
    if (threadIdx.x == 0) {
        int s = 0;
        for (int r = 0; r < 8; ++r) { off[r] = s; cur[r] = s; s += cnt[r]; }
    }
}

__global__ __launch_bounds__(256) void scatter_kernel(
    const int* __restrict__ rinfo, const float* __restrict__ wbuf,
    int* __restrict__ cur, int* __restrict__ ent, float* __restrict__ ewt, int N)
{
    __shared__ int hist[8], lbase[8], lcur[8];
    int tid = threadIdx.x;
    if (tid < 8) { hist[tid] = 0; lcur[tid] = 0; }
    __syncthreads();
    int rows = N >> 8;                 // 256 rows per block, 256 blocks
    int base = blockIdx.x * rows;
    for (int i = tid; i < rows; i += 256) {
        int ri = rinfo[base + i];
        atomicAdd(&hist[ri & 15], 1);
        atomicAdd(&hist[(ri >> 4) & 15], 1);
    }
    __syncthreads();
    if (tid < 8) lbase[tid] = atomicAdd(&cur[tid], hist[tid]);
    __syncthreads();
    for (int i = tid; i < rows; i += 256) {
        int row = base + i;
        int ri = rinfo[row];
        int r0 = ri & 15, r1 = (ri >> 4) & 15;
        int p0 = lbase[r0] + atomicAdd(&lcur[r0], 1);
        ent[p0] = row << 1;       ewt[p0] = wbuf[2 * row];
        int p1 = lbase[r1] + atomicAdd(&lcur[r1], 1);
        ent[p1] = (row << 1) | 1; ewt[p1] = wbuf[2 * row + 1];
    }
}

// ---------------- fused projection GEMM + l2norm + scores + softmax ----------------
// tile: 128 rows x 64 h, 128 threads (2 waves), 8x8 micro-tile, K-chunk 32,
// __launch_bounds__(128,1) (VGPR cap 256 -- the round-0..4 spills were the
// allocator clamping to the 2x-min-waves occupancy entry; confirmed round 5:
// VGPR 116, zero spill).
// ROUND-6 CHANGE: T14 issue-early/write-late staging. Round 5 exposed full
// staging latency each chunk (both waves of a block barrier-locked in phase,
// only 8 waves/CU -> nothing covers the ~700cy HBM load + barrier drain).
// Now: [barrier A] ds_write regs(c) -> LDS; [barrier B] issue global loads
// for c+1 into regs; compute(c). The vmcnt wait for those loads lands at the
// ds_write of iteration c+1, i.e. AFTER compute(c) -- latency hidden within
// the wave. LDS stays 25.6 KB (single buffer), VGPR ~+48 (xv[8]+uv[4]).
__global__ __launch_bounds__(128, 1) void gemm_kernel(
    const float* __restrict__ eh, const float* __restrict__ sr,
    const float* __restrict__ Uw, const float* __restrict__ Ub,
    const float* __restrict__ vl, const int* __restrict__ ent,
    const float* __restrict__ ewt, const int* __restrict__ off,
    const int* __restrict__ cnt, float* __restrict__ probs)
{
    int r = blockIdx.y;
    int count = cnt[r];
    int tile = blockIdx.x;
    if (tile * 128 >= count) return;
    int base = off[r] + tile * 128;

    __shared__ float xs[128 * 32];   // 16 KB, f4-swizzled [row][k4 ^ ((row>>3)&7)]
    __shared__ float us[32 * 64];    // 8 KB, U chunk [k][h]
    __shared__ int   sent[128];
    __shared__ float swt[128];

    int tid = threadIdx.x;
    int tx = tid & 7, ty = tid >> 3;   // ty 0..15, rows 8ty..8ty+7; h 8tx..8tx+7
    float4* xs4 = (float4*)xs;
    float4* us4 = (float4*)us;

    {
        bool act = (tile * 128 + tid) < count;
        sent[tid] = act ? ent[base + tid] : -1;
        swt[tid]  = act ? ewt[base + tid] : 0.f;
    }
    __syncthreads();

    // cache this thread's staging row ids (rloc = ty + 16p)
    int rowp[8];
#pragma unroll
    for (int p = 0; p < 8; ++p) {
        int e = sent[ty + 16 * p];
        rowp[p] = (e < 0) ? 0 : (e >> 1);
    }

    float acc[8][8];
#pragma unroll
    for (int i = 0; i < 8; ++i)
#pragma unroll
        for (int j = 0; j < 8; ++j) acc[i][j] = 0.f;

    // prologue: load chunk 0 into registers
    float4 xv[8], uv[4];
#pragma unroll
    for (int p = 0; p < 8; ++p)
        xv[p] = ((const float4*)(eh + (size_t)rowp[p] * 384))[tx];
    {
        const float4* pu = (const float4*)(Uw + (size_t)r * 768 * 64);
#pragma unroll
        for (int p = 0; p < 4; ++p) uv[p] = pu[tid + p * 128];
    }

    for (int c = 0; c < 24; ++c) {
        __syncthreads();   // A: all waves done reading xs/us of chunk c-1
        {   // write staged chunk c (vmcnt wait here = after compute(c-1))
#pragma unroll
            for (int p = 0; p < 8; ++p) {
                int rloc = ty + 16 * p;
                xs4[rloc * 8 + (tx ^ ((rloc >> 3) & 7))] = xv[p];
            }
#pragma unroll
            for (int p = 0; p < 4; ++p) us4[tid + p * 128] = uv[p];
        }
        __syncthreads();   // B: writes visible
        if (c < 23) {      // issue chunk c+1 loads; consumed next iteration
            int cn = c + 1;
            const float* xsrc = (cn < 12) ? eh : sr;
            int dd0 = ((cn < 12) ? cn : cn - 12) * 32;
#pragma unroll
            for (int p = 0; p < 8; ++p)
                xv[p] = ((const float4*)(xsrc + (size_t)rowp[p] * 384 + dd0))[tx];
            const float4* pu = (const float4*)(Uw + ((size_t)r * 768 + (size_t)cn * 32) * 64);
#pragma unroll
            for (int p = 0; p < 4; ++p) uv[p] = pu[tid + p * 128];
        }
#pragma unroll
        for (int k4 = 0; k4 < 8; ++k4) {
            float4 a[8];
#pragma unroll
            for (int i = 0; i < 8; ++i)
                a[i] = xs4[(8 * ty + i) * 8 + (k4 ^ (ty & 7))];
#pragma unroll
            for (int j = 0; j < 4; ++j) {
                float4 b0 = us4[(k4 * 4 + j) * 16 + tx * 2];
                float4 b1 = us4[(k4 * 4 + j) * 16 + tx * 2 + 1];
#pragma unroll
                for (int i = 0; i < 8; ++i) {
                    float av = (j == 0) ? a[i].x : (j == 1) ? a[i].y : (j == 2) ? a[i].z : a[i].w;
                    acc[i][0] += av * b0.x; acc[i][1] += av * b0.y;
                    acc[i][2] += av * b0.z; acc[i][3] += av * b0.w;
                    acc[i][4] += av * b1.x; acc[i][5] += av * b1.y;
                    acc[i][6] += av * b1.z; acc[i][7] += av * b1.w;
                }
            }
        }
    }
    __syncthreads();   // all compute done before vl staging overwrites xs

    // bias + l2-normalize rows (partial over tx, xor-shfl 1,2,4)
    float ub[8];
#pragma unroll
    for (int j = 0; j < 8; ++j) ub[j] = Ub[r * 64 + 8 * tx + j];
#pragma unroll
    for (int i = 0; i < 8; ++i) {
        float ss = 0.f;
#pragma unroll
        for (int j = 0; j < 8; ++j) { acc[i][j] += ub[j]; ss += acc[i][j] * acc[i][j]; }
#pragma unroll
        for (int m = 1; m <= 4; m <<= 1) ss += __shfl_xor(ss, m);
        float inv = 1.0f / fmaxf(sqrtf(ss), 1e-12f);
#pragma unroll
        for (int j = 0; j < 8; ++j) acc[i][j] *= inv;
    }

    // stage vl[r] (16 KB) into xs, swizzled [h][l4 ^ ((h>>3)&7)]
    {
        const float4* pv = (const float4*)(vl + (size_t)r * 4096);
#pragma unroll
        for (int p = 0; p < 8; ++p) {
            int idx = tid + p * 128;
            int h = idx >> 4, l4 = idx & 15;
            xs4[h * 16 + (l4 ^ ((h >> 3) & 7))] = pv[idx];
        }
    }
    __syncthreads();

    // scores + softmax + store, in four 2-row halves (register pressure)
#pragma unroll
    for (int ih = 0; ih < 8; ih += 2) {
        float sc[2][8];
        for (int lc = 0; lc < 8; ++lc) {
            float part[2][8];
#pragma unroll
            for (int i = 0; i < 2; ++i)
#pragma unroll
                for (int j = 0; j < 8; ++j) part[i][j] = 0.f;
#pragma unroll
            for (int j = 0; j < 8; ++j) {
                int h = 8 * tx + j;
                float4 v0 = xs4[h * 16 + ((2 * lc) ^ tx)];
                float4 v1 = xs4[h * 16 + ((2 * lc + 1) ^ tx)];
#pragma unroll
                for (int i = 0; i < 2; ++i) {
                    float uv2 = acc[ih + i][j];
                    part[i][0] += uv2 * v0.x; part[i][1] += uv2 * v0.y;
                    part[i][2] += uv2 * v0.z; part[i][3] += uv2 * v0.w;
                    part[i][4] += uv2 * v1.x; part[i][5] += uv2 * v1.y;
                    part[i][6] += uv2 * v1.z; part[i][7] += uv2 * v1.w;
                }
            }
#pragma unroll
            for (int m = 1; m <= 4; m <<= 1)
#pragma unroll
                for (int i = 0; i < 2; ++i)
#pragma unroll
                    for (int j = 0; j < 8; ++j) part[i][j] += __shfl_xor(part[i][j], m);
            if (tx == lc) {
#pragma unroll
                for (int i = 0; i < 2; ++i)
#pragma unroll
                    for (int j = 0; j < 8; ++j) sc[i][j] = part[i][j];
            }
        }
#pragma unroll
        for (int i = 0; i < 2; ++i) {
            float mx = sc[i][0];
#pragma unroll
            for (int j = 1; j < 8; ++j) mx = fmaxf(mx, sc[i][j]);
#pragma unroll
            for (int m = 1; m <= 4; m <<= 1) mx = fmaxf(mx, __shfl_xor(mx, m));
            float e[8], ssum = 0.f;
#pragma unroll
            for (int j = 0; j < 8; ++j) { e[j] = expf(sc[i][j] - mx); ssum += e[j]; }
#pragma unroll
            for (int m = 1; m <= 4; m <<= 1) ssum += __shfl_xor(ssum, m);
            int rloc = 8 * ty + ih + i;
            int ei = sent[rloc];
            if (ei >= 0) {
                float w = swt[rloc];
                float4 o0, o1;
                o0.x = (e[0] / ssum) * w; o0.y = (e[1] / ssum) * w;
                o0.z = (e[2] / ssum) * w; o0.w = (e[3] / ssum) * w;
                o1.x = (e[4] / ssum) * w; o1.y = (e[5] / ssum) * w;
                o1.z = (e[6] / ssum) * w; o1.w = (e[7] / ssum) * w;
                size_t bo = (size_t)(ei >> 1) * 128 + (size_t)(ei & 1) * 64 + 8 * tx;
                *(float4*)(probs + bo) = o0;
                *(float4*)(probs + bo + 4) = o1;
            }
        }
    }
}

// ---------------- combine: p = k0+k1, sequential cumsum, select, log ----------------
__global__ __launch_bounds__(256) void combine_kernel(
    const float* __restrict__ probs, const float* __restrict__ rnd,
    float* __restrict__ out, int N)
{
    int w = threadIdx.x >> 6, lane = threadIdx.x & 63;
    int n = blockIdx.x * 4 + w;
    float p = probs[(size_t)n * 128 + lane] + probs[(size_t)n * 128 + 64 + lane];
    float rn = rnd[n];
    float c = 0.f; int sel = 0; bool found = false;
    for (int l = 0; l < 64; ++l) {
        float v = __shfl(p, l);
        c += v;
        if (!found && c > rn) { sel = l; found = true; }
    }
    float pv = __shfl(p, sel);
    if (lane == 0) {
        out[n] = (float)sel;
        out[N + n] = logf(pv);
    }
}

__global__ __launch_bounds__(256) void aux_kernel(const float* __restrict__ aux,
                                                  float* __restrict__ out, int N) {
    __shared__ float red[256];
    int tid = threadIdx.x;
    int j = tid & 15, s0 = tid >> 4;
    float acc = 0.f;
    for (int s = s0; s < AUX_SLOTS; s += 16) acc += aux[s * 16 + j];
    red[tid] = acc;
    __syncthreads();
    if (tid < 16) {
        float a = 0.f;
        for (int g = 0; g < 16; ++g) a += red[g * 16 + tid];
        red[tid] = a;
    }
    __syncthreads();
    if (tid == 0) {
        float invN = 1.f / (float)N;
        float t = 0.f;
        for (int r2 = 0; r2 < 8; ++r2) t += (red[r2] * invN) * (red[8 + r2] * invN);
        out[2 * N] = 8.0f * 0.05f * t;
    }
}

extern "C" void kernel_launch(void* const* d_in, const int* in_sizes, int n_in,
                              void* d_out, int out_size, void* d_ws, size_t ws_size,
                              hipStream_t stream) {
    const float* eh  = (const float*)d_in[0];
    const float* sr  = (const float*)d_in[1];
    const float* llm = (const float*)d_in[2];
    const float* rnd = (const float*)d_in[3];
    const float* gw  = (const float*)d_in[4];
    const float* gb  = (const float*)d_in[5];
    const float* Uw  = (const float*)d_in[6];
    const float* Ub  = (const float*)d_in[7];
    const float* Vw  = (const float*)d_in[8];
    const float* Vb  = (const float*)d_in[9];
    int N = in_sizes[0] / 384;

    float* vl    = (float*)d_ws;              // 32768
    float* aux   = vl + 32768;                // 16384
    int*   cnt   = (int*)(aux + 16384);       // 8
    int*   cur   = cnt + 8;                   // 8
    int*   off   = cur + 8;                   // 8
    int*   rinfo = off + 8;                   // N
    float* wbuf  = (float*)(rinfo + N);       // 2N
    int*   ent   = (int*)(wbuf + 2 * N);      // 2N
    float* ewt   = (float*)(ent + 2 * N);     // 2N
    float* probs = ewt + 2 * N;               // N*128

    hipMemsetAsync(aux, 0, (16384 + 16) * sizeof(float), stream);
    vl_kernel<<<512, 64, 0, stream>>>(llm, Vw, Vb, vl);
    gate_kernel<<<N / 32, 256, 0, stream>>>(eh, sr, gw, gb, rinfo, wbuf, aux, cnt, N);
    prefix_kernel<<<1, 64, 0, stream>>>(cnt, cur, off);
    scatter_kernel<<<256, 256, 0, stream>>>(rinfo, wbuf, cur, ent, ewt, N);
    gemm_kernel<<<dim3(1024, 8), 128, 0, stream>>>(eh, sr, Uw, Ub, vl, ent, ewt,
                                                   off, cnt, probs);
    combine_kernel<<<N / 4, 256, 0, stream>>>(probs, rnd, (float*)d_out, N);
    aux_kernel<<<1, 256, 0, stream>>>(aux, (float*)d_out, N);
}

// Round 7
// 627.680 us; speedup vs baseline: 1.1261x; 1.1261x over previous
//
#include <hip/hip_runtime.h>
#include <math.h>

#define AUX_SLOTS 1024

// direct global->LDS DMA, 16B per lane, wave-uniform LDS base + lane*16
#define GLL16(gp, lp) __builtin_amdgcn_global_load_lds(                      \
    (const __attribute__((address_space(1))) void*)(gp),                     \
    (__attribute__((address_space(3))) void*)(lp), 16, 0, 0)

// ---------------- vl: normalized V-projections, layout [R][H][L] ----------------
__global__ void vl_kernel(const float* __restrict__ llm, const float* __restrict__ Vw,
                          const float* __restrict__ Vb, float* __restrict__ vl) {
    int b = blockIdx.x;          // b = r*64 + l
    int r = b >> 6, l = b & 63;
    int t = threadIdx.x;         // h
    float acc = Vb[r * 64 + t];
    const float* w = Vw + (size_t)(r * 384) * 64 + t;
    const float* xr = llm + l * 384;
#pragma unroll 4
    for (int d = 0; d < 384; ++d) acc += xr[d] * w[(size_t)d * 64];
    float ss = acc * acc;
#pragma unroll
    for (int m = 1; m < 64; m <<= 1) ss += __shfl_xor(ss, m);
    float inv = 1.0f / fmaxf(sqrtf(ss), 1e-12f);
    vl[((size_t)r * 64 + t) * 64 + l] = acc * inv;   // [r][h][l]
}

// ---------------- gate: logits, top-2, aux partials, router counts ----------------
__global__ __launch_bounds__(256) void gate_kernel(
    const float* __restrict__ eh, const float* __restrict__ sr,
    const float* __restrict__ gw, const float* __restrict__ gb,
    int* __restrict__ rinfo, float* __restrict__ wbuf,
    float* __restrict__ aux, int* __restrict__ cnt, int N)
{
    __shared__ int lcnt[8];
    int tid = threadIdx.x;
    if (tid < 8) lcnt[tid] = 0;
    __syncthreads();
    int wave = tid >> 6, lane = tid & 63;
    int wgid = blockIdx.x * 4 + wave;
    float gbr[8];
#pragma unroll
    for (int r = 0; r < 8; ++r) gbr[r] = gb[r];
    float aux_acc = 0.f;

    for (int rr = 0; rr < 8; ++rr) {
        int row = wgid * 8 + rr;
        const float4* pa = (const float4*)(eh + (size_t)row * 384);
        const float4* pb = (const float4*)(sr + (size_t)row * 384);
        float4 xv0 = pa[lane];
        const float4* p1 = (lane < 32) ? (pa + 64 + lane) : (pb + (lane - 32));
        float4 xv1 = *p1;
        float4 xv2 = pb[lane + 32];

        float lg[8];
#pragma unroll
        for (int r = 0; r < 8; ++r) lg[r] = 0.f;
        {
            const float* g0 = gw + (size_t)lane * 32;
            const float* g1 = gw + (size_t)(lane + 64) * 32;
            const float* g2 = gw + (size_t)(lane + 128) * 32;
            float xd;
#pragma unroll
            for (int dd = 0; dd < 4; ++dd) {
                xd = (dd == 0) ? xv0.x : (dd == 1) ? xv0.y : (dd == 2) ? xv0.z : xv0.w;
#pragma unroll
                for (int r = 0; r < 8; ++r) lg[r] += xd * g0[dd * 8 + r];
            }
#pragma unroll
            for (int dd = 0; dd < 4; ++dd) {
                xd = (dd == 0) ? xv1.x : (dd == 1) ? xv1.y : (dd == 2) ? xv1.z : xv1.w;
#pragma unroll
                for (int r = 0; r < 8; ++r) lg[r] += xd * g1[dd * 8 + r];
            }
#pragma unroll
            for (int dd = 0; dd < 4; ++dd) {
                xd = (dd == 0) ? xv2.x : (dd == 1) ? xv2.y : (dd == 2) ? xv2.z : xv2.w;
#pragma unroll
                for (int r = 0; r < 8; ++r) lg[r] += xd * g2[dd * 8 + r];
            }
        }
#pragma unroll
        for (int m = 1; m < 64; m <<= 1) {
#pragma unroll
            for (int r = 0; r < 8; ++r) lg[r] += __shfl_xor(lg[r], m);
        }
#pragma unroll
        for (int r = 0; r < 8; ++r) lg[r] += gbr[r];

        float mx = lg[0];
#pragma unroll
        for (int r = 1; r < 8; ++r) mx = fmaxf(mx, lg[r]);
        float e8[8], se = 0.f;
#pragma unroll
        for (int r = 0; r < 8; ++r) { e8[r] = expf(lg[r] - mx); se += e8[r]; }

        int r0 = 0; float v0 = lg[0];
#pragma unroll
        for (int r = 1; r < 8; ++r) if (lg[r] > v0) { v0 = lg[r]; r0 = r; }
        int r1 = (r0 == 0) ? 1 : 0; float v1 = lg[r1];
#pragma unroll
        for (int r = 0; r < 8; ++r) if (r != r1 && r != r0 && lg[r] > v1) { v1 = lg[r]; r1 = r; }
        float z = expf(v1 - v0);
        float w0 = 1.f / (1.f + z), w1 = z / (1.f + z);

        if (lane == 0) {
            rinfo[row] = r0 | (r1 << 4);
            wbuf[2 * row] = w0; wbuf[2 * row + 1] = w1;
            atomicAdd(&lcnt[r0], 1);
            atomicAdd(&lcnt[r1], 1);
        }
#pragma unroll
        for (int r2 = 0; r2 < 8; ++r2) {
            if (lane == r2) aux_acc += e8[r2] / se;
            if (lane - 8 == r2) aux_acc += (r2 == r0 || r2 == r1) ? 1.f : 0.f;
        }
    }
    if (lane < 16) atomicAdd(aux + ((size_t)(wgid & (AUX_SLOTS - 1)) * 16) + lane, aux_acc);
    __syncthreads();
    if (tid < 8) atomicAdd(&cnt[tid], lcnt[tid]);
}

__global__ void prefix_kernel(const int* __restrict__ cnt, int* __restrict__ cur,
                              int* __restrict__ off) {
    if (threadIdx.x == 0) {
        int s = 0;
        for (int r = 0; r < 8; ++r) { off[r] = s; cur[r] = s; s += cnt[r]; }
    }
}

__global__ __launch_bounds__(256) void scatter_kernel(
    const int* __restrict__ rinfo, const float* __restrict__ wbuf,
    int* __restrict__ cur, int* __restrict__ ent, float* __restrict__ ewt, int N)
{
    __shared__ int hist[8], lbase[8], lcur[8];
    int tid = threadIdx.x;
    if (tid < 8) { hist[tid] = 0; lcur[tid] = 0; }
    __syncthreads();
    int rows = N >> 8;                 // 256 rows per block, 256 blocks
    int base = blockIdx.x * rows;
    for (int i = tid; i < rows; i += 256) {
        int ri = rinfo[base + i];
        atomicAdd(&hist[ri & 15], 1);
        atomicAdd(&hist[(ri >> 4) & 15], 1);
    }
    __syncthreads();
    if (tid < 8) lbase[tid] = atomicAdd(&cur[tid], hist[tid]);
    __syncthreads();
    for (int i = tid; i < rows; i += 256) {
        int row = base + i;
        int ri = rinfo[row];
        int r0 = ri & 15, r1 = (ri >> 4) & 15;
        int p0 = lbase[r0] + atomicAdd(&lcur[r0], 1);
        ent[p0] = row << 1;       ewt[p0] = wbuf[2 * row];
        int p1 = lbase[r1] + atomicAdd(&lcur[r1], 1);
        ent[p1] = (row << 1) | 1; ewt[p1] = wbuf[2 * row + 1];
    }
}

// ---------------- fused projection GEMM + l2norm + scores + softmax ----------------
// tile: 128 rows x 64 h, 128 threads (2 waves), 8x8 micro-tile, K-chunk 32,
// __launch_bounds__(128,1). Staging history: synchronous = 345us (round 5,
// latency exposed); register-prefetch = spills (rounds 3/6: WRITE_SIZE x10,
// the live-set across the FMA body exceeds what the allocator tolerates).
// ROUND-7: global_load_lds DMA staging (zero VGPR cost). LDS double-buffered
// (x 16KBx2 + U 8KBx2 = 48KB, 3 blocks/CU). Per chunk: issue DMA for c+1 ->
// compute(c) -> barrier (compiler's vmcnt(0) drain lands AFTER compute, so
// the ~700cy HBM latency hides under the ~4096cy FMA body; m97 structure).
// Swizzled x layout achieved by pre-swizzling the per-lane GLOBAL source
// column (m173 pattern): LDS dest stays linear in lane, slot formula
// slot(R,k4)=R*8+(k4^((R>>3)&7)) preserved, compute loop unchanged.
__global__ __launch_bounds__(128, 1) void gemm_kernel(
    const float* __restrict__ eh, const float* __restrict__ sr,
    const float* __restrict__ Uw, const float* __restrict__ Ub,
    const float* __restrict__ vl, const int* __restrict__ ent,
    const float* __restrict__ ewt, const int* __restrict__ off,
    const int* __restrict__ cnt, float* __restrict__ probs)
{
    int r = blockIdx.y;
    int count = cnt[r];
    int tile = blockIdx.x;
    if (tile * 128 >= count) return;
    int base = off[r] + tile * 128;

    __shared__ float4 xs4[2048];   // 32 KB: two 1024-f4 x buffers
    __shared__ float4 us4[1024];   // 16 KB: two 512-f4 U buffers
    __shared__ int    sent[128];
    __shared__ float  swt[128];

    int tid = threadIdx.x;
    int tx = tid & 7, ty = tid >> 3;   // ty 0..15, rows 8ty..8ty+7; h 8tx..8tx+7
    int wid = tid >> 6;                // wave id 0/1

    {
        bool act = (tile * 128 + tid) < count;
        sent[tid] = act ? ent[base + tid] : -1;
        swt[tid]  = act ? ewt[base + tid] : 0.f;
    }
    __syncthreads();

    // staging row ids: lane's own rowp[p] is exactly the row its DMA slot needs
    // (slot l of (wave w, call p) holds row 16p + 8w + (l>>3) = 16p + ty)
    int rowp[8];
#pragma unroll
    for (int p = 0; p < 8; ++p) {
        int e = sent[ty + 16 * p];
        rowp[p] = (e < 0) ? 0 : (e >> 1);
    }

    float acc[8][8];
#pragma unroll
    for (int i = 0; i < 8; ++i)
#pragma unroll
        for (int j = 0; j < 8; ++j) acc[i][j] = 0.f;

    // prologue: DMA chunk 0 into buffer 0, then drain
    {
#pragma unroll
        for (int p = 0; p < 8; ++p) {
            int cwp = (2 * p + wid) & 7;
            const float* gp = eh + (size_t)rowp[p] * 384 + ((tx ^ cwp) << 2);
            GLL16(gp, xs4 + p * 128 + wid * 64);
        }
        const float4* pu = (const float4*)(Uw + (size_t)r * 768 * 64);
#pragma unroll
        for (int p = 0; p < 4; ++p)
            GLL16(pu + p * 128 + tid, us4 + p * 128 + wid * 64);
    }
    __syncthreads();   // vmcnt(0) drain: buffer 0 ready

    for (int c = 0; c < 24; ++c) {
        int cb = (c & 1);
        if (c < 23) {   // issue DMA for c+1 into the other buffer
            int cn = c + 1;
            const float* xsrc = (cn < 12) ? eh : sr;
            int dd0 = ((cn < 12) ? cn : cn - 12) * 32;
            int nb = (cn & 1);
#pragma unroll
            for (int p = 0; p < 8; ++p) {
                int cwp = (2 * p + wid) & 7;
                const float* gp = xsrc + (size_t)rowp[p] * 384 + dd0 + ((tx ^ cwp) << 2);
                GLL16(gp, xs4 + nb * 1024 + p * 128 + wid * 64);
            }
            const float4* pu = (const float4*)(Uw + ((size_t)r * 768 + (size_t)cn * 32) * 64);
#pragma unroll
            for (int p = 0; p < 4; ++p)
                GLL16(pu + p * 128 + tid, us4 + nb * 512 + p * 128 + wid * 64);
        }
        const float4* xb = xs4 + cb * 1024;
        const float4* ub = us4 + cb * 512;
#pragma unroll
        for (int k4 = 0; k4 < 8; ++k4) {
            float4 a[8];
#pragma unroll
            for (int i = 0; i < 8; ++i)
                a[i] = xb[(8 * ty + i) * 8 + (k4 ^ (ty & 7))];
#pragma unroll
            for (int j = 0; j < 4; ++j) {
                float4 b0 = ub[(k4 * 4 + j) * 16 + tx * 2];
                float4 b1 = ub[(k4 * 4 + j) * 16 + tx * 2 + 1];
#pragma unroll
                for (int i = 0; i < 8; ++i) {
                    float av = (j == 0) ? a[i].x : (j == 1) ? a[i].y : (j == 2) ? a[i].z : a[i].w;
                    acc[i][0] += av * b0.x; acc[i][1] += av * b0.y;
                    acc[i][2] += av * b0.z; acc[i][3] += av * b0.w;
                    acc[i][4] += av * b1.x; acc[i][5] += av * b1.y;
                    acc[i][6] += av * b1.z; acc[i][7] += av * b1.w;
                }
            }
        }
        __syncthreads();   // drains c+1 DMA (already landed under compute) +
                           // orders: next issue may overwrite buf read this iter
    }

    // bias + l2-normalize rows (partial over tx, xor-shfl 1,2,4)
    float ubias[8];
#pragma unroll
    for (int j = 0; j < 8; ++j) ubias[j] = Ub[r * 64 + 8 * tx + j];
#pragma unroll
    for (int i = 0; i < 8; ++i) {
        float ss = 0.f;
#pragma unroll
        for (int j = 0; j < 8; ++j) { acc[i][j] += ubias[j]; ss += acc[i][j] * acc[i][j]; }
#pragma unroll
        for (int m = 1; m <= 4; m <<= 1) ss += __shfl_xor(ss, m);
        float inv = 1.0f / fmaxf(sqrtf(ss), 1e-12f);
#pragma unroll
        for (int j = 0; j < 8; ++j) acc[i][j] *= inv;
    }

    // stage vl[r] (16 KB) into xs buffer 0, swizzled [h][l4 ^ ((h>>3)&7)]
    {
        const float4* pv = (const float4*)(vl + (size_t)r * 4096);
#pragma unroll
        for (int p = 0; p < 8; ++p) {
            int idx = tid + p * 128;
            int h = idx >> 4, l4 = idx & 15;
            xs4[h * 16 + (l4 ^ ((h >> 3) & 7))] = pv[idx];
        }
    }
    __syncthreads();

    // scores + softmax + store, in four 2-row halves (register pressure)
#pragma unroll
    for (int ih = 0; ih < 8; ih += 2) {
        float sc[2][8];
        for (int lc = 0; lc < 8; ++lc) {
            float part[2][8];
#pragma unroll
            for (int i = 0; i < 2; ++i)
#pragma unroll
                for (int j = 0; j < 8; ++j) part[i][j] = 0.f;
#pragma unroll
            for (int j = 0; j < 8; ++j) {
                int h = 8 * tx + j;
                float4 v0 = xs4[h * 16 + ((2 * lc) ^ tx)];
                float4 v1 = xs4[h * 16 + ((2 * lc + 1) ^ tx)];
#pragma unroll
                for (int i = 0; i < 2; ++i) {
                    float uv2 = acc[ih + i][j];
                    part[i][0] += uv2 * v0.x; part[i][1] += uv2 * v0.y;
                    part[i][2] += uv2 * v0.z; part[i][3] += uv2 * v0.w;
                    part[i][4] += uv2 * v1.x; part[i][5] += uv2 * v1.y;
                    part[i][6] += uv2 * v1.z; part[i][7] += uv2 * v1.w;
                }
            }
#pragma unroll
            for (int m = 1; m <= 4; m <<= 1)
#pragma unroll
                for (int i = 0; i < 2; ++i)
#pragma unroll
                    for (int j = 0; j < 8; ++j) part[i][j] += __shfl_xor(part[i][j], m);
            if (tx == lc) {
#pragma unroll
                for (int i = 0; i < 2; ++i)
#pragma unroll
                    for (int j = 0; j < 8; ++j) sc[i][j] = part[i][j];
            }
        }
#pragma unroll
        for (int i = 0; i < 2; ++i) {
            float mx = sc[i][0];
#pragma unroll
            for (int j = 1; j < 8; ++j) mx = fmaxf(mx, sc[i][j]);
#pragma unroll
            for (int m = 1; m <= 4; m <<= 1) mx = fmaxf(mx, __shfl_xor(mx, m));
            float e[8], ssum = 0.f;
#pragma unroll
            for (int j = 0; j < 8; ++j) { e[j] = expf(sc[i][j] - mx); ssum += e[j]; }
#pragma unroll
            for (int m = 1; m <= 4; m <<= 1) ssum += __shfl_xor(ssum, m);
            int rloc = 8 * ty + ih + i;
            int ei = sent[rloc];
            if (ei >= 0) {
                float w = swt[rloc];
                float4 o0, o1;
                o0.x = (e[0] / ssum) * w; o0.y = (e[1] / ssum) * w;
                o0.z = (e[2] / ssum) * w; o0.w = (e[3] / ssum) * w;
                o1.x = (e[4] / ssum) * w; o1.y = (e[5] / ssum) * w;
                o1.z = (e[6] / ssum) * w; o1.w = (e[7] / ssum) * w;
                size_t bo = (size_t)(ei >> 1) * 128 + (size_t)(ei & 1) * 64 + 8 * tx;
                *(float4*)(probs + bo) = o0;
                *(float4*)(probs + bo + 4) = o1;
            }
        }
    }
}

// ---------------- combine: p = k0+k1, sequential cumsum, select, log ----------------
__global__ __launch_bounds__(256) void combine_kernel(
    const float* __restrict__ probs, const float* __restrict__ rnd,
    float* __restrict__ out, int N)
{
    int w = threadIdx.x >> 6, lane = threadIdx.x & 63;
    int n = blockIdx.x * 4 + w;
    float p = probs[(size_t)n * 128 + lane] + probs[(size_t)n * 128 + 64 + lane];
    float rn = rnd[n];
    float c = 0.f; int sel = 0; bool found = false;
    for (int l = 0; l < 64; ++l) {
        float v = __shfl(p, l);
        c += v;
        if (!found && c > rn) { sel = l; found = true; }
    }
    float pv = __shfl(p, sel);
    if (lane == 0) {
        out[n] = (float)sel;
        out[N + n] = logf(pv);
    }
}

__global__ __launch_bounds__(256) void aux_kernel(const float* __restrict__ aux,
                                                  float* __restrict__ out, int N) {
    __shared__ float red[256];
    int tid = threadIdx.x;
    int j = tid & 15, s0 = tid >> 4;
    float acc = 0.f;
    for (int s = s0; s < AUX_SLOTS; s += 16) acc += aux[s * 16 + j];
    red[tid] = acc;
    __syncthreads();
    if (tid < 16) {
        float a = 0.f;
        for (int g = 0; g < 16; ++g) a += red[g * 16 + tid];
        red[tid] = a;
    }
    __syncthreads();
    if (tid == 0) {
        float invN = 1.f / (float)N;
        float t = 0.f;
        for (int r2 = 0; r2 < 8; ++r2) t += (red[r2] * invN) * (red[8 + r2] * invN);
        out[2 * N] = 8.0f * 0.05f * t;
    }
}

extern "C" void kernel_launch(void* const* d_in, const int* in_sizes, int n_in,
                              void* d_out, int out_size, void* d_ws, size_t ws_size,
                              hipStream_t stream) {
    const float* eh  = (const float*)d_in[0];
    const float* sr  = (const float*)d_in[1];
    const float* llm = (const float*)d_in[2];
    const float* rnd = (const float*)d_in[3];
    const float* gw  = (const float*)d_in[4];
    const float* gb  = (const float*)d_in[5];
    const float* Uw  = (const float*)d_in[6];
    const float* Ub  = (const float*)d_in[7];
    const float* Vw  = (const float*)d_in[8];
    const float* Vb  = (const float*)d_in[9];
    int N = in_sizes[0] / 384;

    float* vl    = (float*)d_ws;              // 32768
    float* aux   = vl + 32768;                // 16384
    int*   cnt   = (int*)(aux + 16384);       // 8
    int*   cur   = cnt + 8;                   // 8
    int*   off   = cur + 8;                   // 8
    int*   rinfo = off + 8;                   // N
    float* wbuf  = (float*)(rinfo + N);       // 2N
    int*   ent   = (int*)(wbuf + 2 * N);      // 2N
    float* ewt   = (float*)(ent + 2 * N);     // 2N
    float* probs = ewt + 2 * N;               // N*128

    hipMemsetAsync(aux, 0, (16384 + 16) * sizeof(float), stream);
    vl_kernel<<<512, 64, 0, stream>>>(llm, Vw, Vb, vl);
    gate_kernel<<<N / 32, 256, 0, stream>>>(eh, sr, gw, gb, rinfo, wbuf, aux, cnt, N);
    prefix_kernel<<<1, 64, 0, stream>>>(cnt, cur, off);
    scatter_kernel<<<256, 256, 0, stream>>>(rinfo, wbuf, cur, ent, ewt, N);
    gemm_kernel<<<dim3(1024, 8), 128, 0, stream>>>(eh, sr, Uw, Ub, vl, ent, ewt,
                                                   off, cnt, probs);
    combine_kernel<<<N / 4, 256, 0, stream>>>(probs, rnd, (float*)d_out, N);
    aux_kernel<<<1, 256, 0, stream>>>(aux, (float*)d_out, N);
}

// Round 8
// 598.185 us; speedup vs baseline: 1.1816x; 1.0493x over previous
//
#include <hip/hip_runtime.h>
#include <math.h>

#define AUX_SLOTS 1024

// ---------------- vl: normalized V-projections, layout [R][H][L] ----------------
__global__ void vl_kernel(const float* __restrict__ llm, const float* __restrict__ Vw,
                          const float* __restrict__ Vb, float* __restrict__ vl) {
    int b = blockIdx.x;          // b = r*64 + l
    int r = b >> 6, l = b & 63;
    int t = threadIdx.x;         // h
    float acc = Vb[r * 64 + t];
    const float* w = Vw + (size_t)(r * 384) * 64 + t;
    const float* xr = llm + l * 384;
#pragma unroll 4
    for (int d = 0; d < 384; ++d) acc += xr[d] * w[(size_t)d * 64];
    float ss = acc * acc;
#pragma unroll
    for (int m = 1; m < 64; m <<= 1) ss += __shfl_xor(ss, m);
    float inv = 1.0f / fmaxf(sqrtf(ss), 1e-12f);
    vl[((size_t)r * 64 + t) * 64 + l] = acc * inv;   // [r][h][l]
}

// ---------------- gate: logits, top-2, aux partials, router counts ----------------
__global__ __launch_bounds__(256) void gate_kernel(
    const float* __restrict__ eh, const float* __restrict__ sr,
    const float* __restrict__ gw, const float* __restrict__ gb,
    int* __restrict__ rinfo, float* __restrict__ wbuf,
    float* __restrict__ aux, int* __restrict__ cnt, int N)
{
    __shared__ int lcnt[8];
    int tid = threadIdx.x;
    if (tid < 8) lcnt[tid] = 0;
    __syncthreads();
    int wave = tid >> 6, lane = tid & 63;
    int wgid = blockIdx.x * 4 + wave;
    float gbr[8];
#pragma unroll
    for (int r = 0; r < 8; ++r) gbr[r] = gb[r];
    float aux_acc = 0.f;

    for (int rr = 0; rr < 8; ++rr) {
        int row = wgid * 8 + rr;
        const float4* pa = (const float4*)(eh + (size_t)row * 384);
        const float4* pb = (const float4*)(sr + (size_t)row * 384);
        float4 xv0 = pa[lane];
        const float4* p1 = (lane < 32) ? (pa + 64 + lane) : (pb + (lane - 32));
        float4 xv1 = *p1;
        float4 xv2 = pb[lane + 32];

        float lg[8];
#pragma unroll
        for (int r = 0; r < 8; ++r) lg[r] = 0.f;
        {
            const float* g0 = gw + (size_t)lane * 32;
            const float* g1 = gw + (size_t)(lane + 64) * 32;
            const float* g2 = gw + (size_t)(lane + 128) * 32;
            float xd;
#pragma unroll
            for (int dd = 0; dd < 4; ++dd) {
                xd = (dd == 0) ? xv0.x : (dd == 1) ? xv0.y : (dd == 2) ? xv0.z : xv0.w;
#pragma unroll
                for (int r = 0; r < 8; ++r) lg[r] += xd * g0[dd * 8 + r];
            }
#pragma unroll
            for (int dd = 0; dd < 4; ++dd) {
                xd = (dd == 0) ? xv1.x : (dd == 1) ? xv1.y : (dd == 2) ? xv1.z : xv1.w;
#pragma unroll
                for (int r = 0; r < 8; ++r) lg[r] += xd * g1[dd * 8 + r];
            }
#pragma unroll
            for (int dd = 0; dd < 4; ++dd) {
                xd = (dd == 0) ? xv2.x : (dd == 1) ? xv2.y : (dd == 2) ? xv2.z : xv2.w;
#pragma unroll
                for (int r = 0; r < 8; ++r) lg[r] += xd * g2[dd * 8 + r];
            }
        }
#pragma unroll
        for (int m = 1; m < 64; m <<= 1) {
#pragma unroll
            for (int r = 0; r < 8; ++r) lg[r] += __shfl_xor(lg[r], m);
        }
#pragma unroll
        for (int r = 0; r < 8; ++r) lg[r] += gbr[r];

        float mx = lg[0];
#pragma unroll
        for (int r = 1; r < 8; ++r) mx = fmaxf(mx, lg[r]);
        float e8[8], se = 0.f;
#pragma unroll
        for (int r = 0; r < 8; ++r) { e8[r] = expf(lg[r] - mx); se += e8[r]; }

        int r0 = 0; float v0 = lg[0];
#pragma unroll
        for (int r = 1; r < 8; ++r) if (lg[r] > v0) { v0 = lg[r]; r0 = r; }
        int r1 = (r0 == 0) ? 1 : 0; float v1 = lg[r1];
#pragma unroll
        for (int r = 0; r < 8; ++r) if (r != r1 && r != r0 && lg[r] > v1) { v1 = lg[r]; r1 = r; }
        float z = expf(v1 - v0);
        float w0 = 1.f / (1.f + z), w1 = z / (1.f + z);

        if (lane == 0) {
            rinfo[row] = r0 | (r1 << 4);
            wbuf[2 * row] = w0; wbuf[2 * row + 1] = w1;
            atomicAdd(&lcnt[r0], 1);
            atomicAdd(&lcnt[r1], 1);
        }
#pragma unroll
        for (int r2 = 0; r2 < 8; ++r2) {
            if (lane == r2) aux_acc += e8[r2] / se;
            if (lane - 8 == r2) aux_acc += (r2 == r0 || r2 == r1) ? 1.f : 0.f;
        }
    }
    if (lane < 16) atomicAdd(aux + ((size_t)(wgid & (AUX_SLOTS - 1)) * 16) + lane, aux_acc);
    __syncthreads();
    if (tid < 8) atomicAdd(&cnt[tid], lcnt[tid]);
}

__global__ void prefix_kernel(const int* __restrict__ cnt, int* __restrict__ cur,
                              int* __restrict__ off) {
    if (threadIdx.x == 0) {
        int s = 0;
        for (int r = 0; r < 8; ++r) { off[r] = s; cur[r] = s; s += cnt[r]; }
    }
}

__global__ __launch_bounds__(256) void scatter_kernel(
    const int* __restrict__ rinfo, const float* __restrict__ wbuf,
    int* __restrict__ cur, int* __restrict__ ent, float* __restrict__ ewt, int N)
{
    __shared__ int hist[8], lbase[8], lcur[8];
    int tid = threadIdx.x;
    if (tid < 8) { hist[tid] = 0; lcur[tid] = 0; }
    __syncthreads();
    int rows = N >> 8;                 // 256 rows per block, 256 blocks
    int base = blockIdx.x * rows;
    for (int i = tid; i < rows; i += 256) {
        int ri = rinfo[base + i];
        atomicAdd(&hist[ri & 15], 1);
        atomicAdd(&hist[(ri >> 4) & 15], 1);
    }
    __syncthreads();
    if (tid < 8) lbase[tid] = atomicAdd(&cur[tid], hist[tid]);
    __syncthreads();
    for (int i = tid; i < rows; i += 256) {
        int row = base + i;
        int ri = rinfo[row];
        int r0 = ri & 15, r1 = (ri >> 4) & 15;
        int p0 = lbase[r0] + atomicAdd(&lcur[r0], 1);
        ent[p0] = row << 1;       ewt[p0] = wbuf[2 * row];
        int p1 = lbase[r1] + atomicAdd(&lcur[r1], 1);
        ent[p1] = (row << 1) | 1; ewt[p1] = wbuf[2 * row + 1];
    }
}

// ---------------- fused projection GEMM + l2norm + scores + softmax ----------------
// ROUND-8: in-block K-split. Ledger: r2 (4x8,256thr,sync)=283us LDS-bound
// (1.5 B/FMA, 16 w/CU); r5 (8x8,128thr,sync)=345us latency-bound (1.0 B/FMA
// but only 8 w/CU, LDS pipe 39% busy); all pipelining variants lost (reg
// prefetch spills r3/r6; DMA addressing blew VGPR to 232, r7).
// This kernel: 256 threads on the 128-row tile; waves 0-1 compute the eh
// K-half, waves 2-3 the sr K-half (12 chunks each, own 24KB buffer, the
// proven r5 8x8 sync loop). LDS 50KB -> 3 blocks/CU = 12 waves/CU (vs r5's
// 8) at r5's 1.0 B/FMA traffic. Epilogue: half-1 writes partial acc to LDS
// scratch (2-way banked = free), half-0 adds + l2norm + scores (unchanged
// r5 code); half-1 helps stage vl then runs out (no barriers after).
// __launch_bounds__(256,1): VGPR cap 256 (allocator law rounds 0-5).
__global__ __launch_bounds__(256, 1) void gemm_kernel(
    const float* __restrict__ eh, const float* __restrict__ sr,
    const float* __restrict__ Uw, const float* __restrict__ Ub,
    const float* __restrict__ vl, const int* __restrict__ ent,
    const float* __restrict__ ewt, const int* __restrict__ off,
    const int* __restrict__ cnt, float* __restrict__ probs)
{
    int r = blockIdx.y;
    int count = cnt[r];
    int tile = blockIdx.x;
    if (tile * 128 >= count) return;
    int base = off[r] + tile * 128;

    __shared__ float4 xs4[2048];   // 32 KB: two 1024-f4 x buffers (one per K-half)
    __shared__ float4 us4[1024];   // 16 KB: two 512-f4 U buffers; vl buffer in epilogue
    __shared__ int    sent[128];
    __shared__ float  swt[128];

    int tid = threadIdx.x;
    int kh = tid >> 7;                  // K-half: waves 0-1 -> 0 (eh), waves 2-3 -> 1 (sr)
    int htid = tid & 127;
    int tx = htid & 7, ty = htid >> 3;  // ty 0..15, rows 8ty..8ty+7; h 8tx..8tx+7

    if (tid < 128) {
        bool act = (tile * 128 + tid) < count;
        sent[tid] = act ? ent[base + tid] : -1;
        swt[tid]  = act ? ewt[base + tid] : 0.f;
    }
    __syncthreads();

    // staging row ids (rloc = ty + 16p) -- identical for both halves
    int rowp[8];
#pragma unroll
    for (int p = 0; p < 8; ++p) {
        int e = sent[ty + 16 * p];
        rowp[p] = (e < 0) ? 0 : (e >> 1);
    }

    float acc[8][8];
#pragma unroll
    for (int i = 0; i < 8; ++i)
#pragma unroll
        for (int j = 0; j < 8; ++j) acc[i][j] = 0.f;

    const float* xsrc = kh ? sr : eh;       // half 0: eh (K 0..383), half 1: sr (K 384..767)
    int koff = kh * 384;
    float4* xb = xs4 + kh * 1024;
    float4* ub = us4 + kh * 512;

    for (int c = 0; c < 12; ++c) {
        int dd0 = c * 32;
        {   // stage x: 8 f4 per thread, swizzled [row][k4 ^ ((row>>3)&7)]
#pragma unroll
            for (int p = 0; p < 8; ++p) {
                int rloc = ty + 16 * p;
                float4 v = ((const float4*)(xsrc + (size_t)rowp[p] * 384 + dd0))[tx];
                xb[rloc * 8 + (tx ^ ((rloc >> 3) & 7))] = v;
            }
        }
        {   // stage U chunk [32k][64h] for this half
            const float4* pu = (const float4*)(Uw + ((size_t)r * 768 + koff + dd0) * 64);
#pragma unroll
            for (int p = 0; p < 4; ++p) ub[htid + p * 128] = pu[htid + p * 128];
        }
        __syncthreads();
#pragma unroll
        for (int k4 = 0; k4 < 8; ++k4) {
            float4 a[8];
#pragma unroll
            for (int i = 0; i < 8; ++i)
                a[i] = xb[(8 * ty + i) * 8 + (k4 ^ (ty & 7))];
#pragma unroll
            for (int j = 0; j < 4; ++j) {
                float4 b0 = ub[(k4 * 4 + j) * 16 + tx * 2];
                float4 b1 = ub[(k4 * 4 + j) * 16 + tx * 2 + 1];
#pragma unroll
                for (int i = 0; i < 8; ++i) {
                    float av = (j == 0) ? a[i].x : (j == 1) ? a[i].y : (j == 2) ? a[i].z : a[i].w;
                    acc[i][0] += av * b0.x; acc[i][1] += av * b0.y;
                    acc[i][2] += av * b0.z; acc[i][3] += av * b0.w;
                    acc[i][4] += av * b1.x; acc[i][5] += av * b1.y;
                    acc[i][6] += av * b1.z; acc[i][7] += av * b1.w;
                }
            }
        }
        __syncthreads();
    }

    // ---- K-half reduction: half-1 writes partials to scratch (xs region) ----
    if (kh == 1) {
#pragma unroll
        for (int i = 0; i < 8; ++i) {
            int row = 8 * ty + i;
            xs4[row * 16 + 2 * tx]     = make_float4(acc[i][0], acc[i][1], acc[i][2], acc[i][3]);
            xs4[row * 16 + 2 * tx + 1] = make_float4(acc[i][4], acc[i][5], acc[i][6], acc[i][7]);
        }
    }
    // stage vl[r] (16 KB) into us region, swizzled [h][l4 ^ ((h>>3)&7)], all 256 threads
    {
        const float4* pv = (const float4*)(vl + (size_t)r * 4096);
#pragma unroll
        for (int p = 0; p < 4; ++p) {
            int idx = tid + p * 256;
            int h = idx >> 4, l4 = idx & 15;
            us4[h * 16 + (l4 ^ ((h >> 3) & 7))] = pv[idx];
        }
    }
    __syncthreads();
    // NO barriers below this point: half-1 waves simply run out.

    if (kh == 0) {
        // add half-1 partials
#pragma unroll
        for (int i = 0; i < 8; ++i) {
            int row = 8 * ty + i;
            float4 s0 = xs4[row * 16 + 2 * tx];
            float4 s1 = xs4[row * 16 + 2 * tx + 1];
            acc[i][0] += s0.x; acc[i][1] += s0.y; acc[i][2] += s0.z; acc[i][3] += s0.w;
            acc[i][4] += s1.x; acc[i][5] += s1.y; acc[i][6] += s1.z; acc[i][7] += s1.w;
        }

        // bias + l2-normalize rows (partial over tx, xor-shfl 1,2,4)
        float ubias[8];
#pragma unroll
        for (int j = 0; j < 8; ++j) ubias[j] = Ub[r * 64 + 8 * tx + j];
#pragma unroll
        for (int i = 0; i < 8; ++i) {
            float ss = 0.f;
#pragma unroll
            for (int j = 0; j < 8; ++j) { acc[i][j] += ubias[j]; ss += acc[i][j] * acc[i][j]; }
#pragma unroll
            for (int m = 1; m <= 4; m <<= 1) ss += __shfl_xor(ss, m);
            float inv = 1.0f / fmaxf(sqrtf(ss), 1e-12f);
#pragma unroll
            for (int j = 0; j < 8; ++j) acc[i][j] *= inv;
        }

        // scores + softmax + store, in four 2-row halves (register pressure)
#pragma unroll
        for (int ih = 0; ih < 8; ih += 2) {
            float sc[2][8];
            for (int lc = 0; lc < 8; ++lc) {
                float part[2][8];
#pragma unroll
                for (int i = 0; i < 2; ++i)
#pragma unroll
                    for (int j = 0; j < 8; ++j) part[i][j] = 0.f;
#pragma unroll
                for (int j = 0; j < 8; ++j) {
                    int h = 8 * tx + j;
                    float4 v0 = us4[h * 16 + ((2 * lc) ^ tx)];
                    float4 v1 = us4[h * 16 + ((2 * lc + 1) ^ tx)];
#pragma unroll
                    for (int i = 0; i < 2; ++i) {
                        float uv2 = acc[ih + i][j];
                        part[i][0] += uv2 * v0.x; part[i][1] += uv2 * v0.y;
                        part[i][2] += uv2 * v0.z; part[i][3] += uv2 * v0.w;
                        part[i][4] += uv2 * v1.x; part[i][5] += uv2 * v1.y;
                        part[i][6] += uv2 * v1.z; part[i][7] += uv2 * v1.w;
                    }
                }
#pragma unroll
                for (int m = 1; m <= 4; m <<= 1)
#pragma unroll
                    for (int i = 0; i < 2; ++i)
#pragma unroll
                        for (int j = 0; j < 8; ++j) part[i][j] += __shfl_xor(part[i][j], m);
                if (tx == lc) {
#pragma unroll
                    for (int i = 0; i < 2; ++i)
#pragma unroll
                        for (int j = 0; j < 8; ++j) sc[i][j] = part[i][j];
                }
            }
#pragma unroll
            for (int i = 0; i < 2; ++i) {
                float mx = sc[i][0];
#pragma unroll
                for (int j = 1; j < 8; ++j) mx = fmaxf(mx, sc[i][j]);
#pragma unroll
                for (int m = 1; m <= 4; m <<= 1) mx = fmaxf(mx, __shfl_xor(mx, m));
                float e[8], ssum = 0.f;
#pragma unroll
                for (int j = 0; j < 8; ++j) { e[j] = expf(sc[i][j] - mx); ssum += e[j]; }
#pragma unroll
                for (int m = 1; m <= 4; m <<= 1) ssum += __shfl_xor(ssum, m);
                int rloc = 8 * ty + ih + i;
                int ei = sent[rloc];
                if (ei >= 0) {
                    float w = swt[rloc];
                    float4 o0, o1;
                    o0.x = (e[0] / ssum) * w; o0.y = (e[1] / ssum) * w;
                    o0.z = (e[2] / ssum) * w; o0.w = (e[3] / ssum) * w;
                    o1.x = (e[4] / ssum) * w; o1.y = (e[5] / ssum) * w;
                    o1.z = (e[6] / ssum) * w; o1.w = (e[7] / ssum) * w;
                    size_t bo = (size_t)(ei >> 1) * 128 + (size_t)(ei & 1) * 64 + 8 * tx;
                    *(float4*)(probs + bo) = o0;
                    *(float4*)(probs + bo + 4) = o1;
                }
            }
        }
    }
}

// ---------------- combine: p = k0+k1, sequential cumsum, select, log ----------------
__global__ __launch_bounds__(256) void combine_kernel(
    const float* __restrict__ probs, const float* __restrict__ rnd,
    float* __restrict__ out, int N)
{
    int w = threadIdx.x >> 6, lane = threadIdx.x & 63;
    int n = blockIdx.x * 4 + w;
    float p = probs[(size_t)n * 128 + lane] + probs[(size_t)n * 128 + 64 + lane];
    float rn = rnd[n];
    float c = 0.f; int sel = 0; bool found = false;
    for (int l = 0; l < 64; ++l) {
        float v = __shfl(p, l);
        c += v;
        if (!found && c > rn) { sel = l; found = true; }
    }
    float pv = __shfl(p, sel);
    if (lane == 0) {
        out[n] = (float)sel;
        out[N + n] = logf(pv);
    }
}

__global__ __launch_bounds__(256) void aux_kernel(const float* __restrict__ aux,
                                                  float* __restrict__ out, int N) {
    __shared__ float red[256];
    int tid = threadIdx.x;
    int j = tid & 15, s0 = tid >> 4;
    float acc = 0.f;
    for (int s = s0; s < AUX_SLOTS; s += 16) acc += aux[s * 16 + j];
    red[tid] = acc;
    __syncthreads();
    if (tid < 16) {
        float a = 0.f;
        for (int g = 0; g < 16; ++g) a += red[g * 16 + tid];
        red[tid] = a;
    }
    __syncthreads();
    if (tid == 0) {
        float invN = 1.f / (float)N;
        float t = 0.f;
        for (int r2 = 0; r2 < 8; ++r2) t += (red[r2] * invN) * (red[8 + r2] * invN);
        out[2 * N] = 8.0f * 0.05f * t;
    }
}

extern "C" void kernel_launch(void* const* d_in, const int* in_sizes, int n_in,
                              void* d_out, int out_size, void* d_ws, size_t ws_size,
                              hipStream_t stream) {
    const float* eh  = (const float*)d_in[0];
    const float* sr  = (const float*)d_in[1];
    const float* llm = (const float*)d_in[2];
    const float* rnd = (const float*)d_in[3];
    const float* gw  = (const float*)d_in[4];
    const float* gb  = (const float*)d_in[5];
    const float* Uw  = (const float*)d_in[6];
    const float* Ub  = (const float*)d_in[7];
    const float* Vw  = (const float*)d_in[8];
    const float* Vb  = (const float*)d_in[9];
    int N = in_sizes[0] / 384;

    float* vl    = (float*)d_ws;              // 32768
    float* aux   = vl + 32768;                // 16384
    int*   cnt   = (int*)(aux + 16384);       // 8
    int*   cur   = cnt + 8;                   // 8
    int*   off   = cur + 8;                   // 8
    int*   rinfo = off + 8;                   // N
    float* wbuf  = (float*)(rinfo + N);       // 2N
    int*   ent   = (int*)(wbuf + 2 * N);      // 2N
    float* ewt   = (float*)(ent + 2 * N);     // 2N
    float* probs = ewt + 2 * N;               // N*128

    hipMemsetAsync(aux, 0, (16384 + 16) * sizeof(float), stream);
    vl_kernel<<<512, 64, 0, stream>>>(llm, Vw, Vb, vl);
    gate_kernel<<<N / 32, 256, 0, stream>>>(eh, sr, gw, gb, rinfo, wbuf, aux, cnt, N);
    prefix_kernel<<<1, 64, 0, stream>>>(cnt, cur, off);
    scatter_kernel<<<256, 256, 0, stream>>>(rinfo, wbuf, cur, ent, ewt, N);
    gemm_kernel<<<dim3(1024, 8), 256, 0, stream>>>(eh, sr, Uw, Ub, vl, ent, ewt,
                                                   off, cnt, probs);
    combine_kernel<<<N / 4, 256, 0, stream>>>(probs, rnd, (float*)d_out, N);
    aux_kernel<<<1, 256, 0, stream>>>(aux, (float*)d_out, N);
}

// Round 9
// 433.576 us; speedup vs baseline: 1.6302x; 1.3797x over previous
//
#include <hip/hip_runtime.h>
#include <math.h>

#define AUX_SLOTS 1024
#define CAP 24576   // per-router ent segment capacity (expected count ~16384, sigma ~150)

// ---------------- vl: normalized V-projections, layout [R][H][L] ----------------
// 256 threads: 4 waves split the 384-dim dot (96 dims each), LDS reduce.
// (old 64-thread version was latency-bound at 2 waves/CU)
__global__ __launch_bounds__(256) void vl_kernel(const float* __restrict__ llm,
                                                 const float* __restrict__ Vw,
                                                 const float* __restrict__ Vb,
                                                 float* __restrict__ vl) {
    int b = blockIdx.x;          // b = r*64 + l
    int r = b >> 6, l = b & 63;
    int tid = threadIdx.x;
    int t = tid & 63, q = tid >> 6;    // t = h, q = K-quarter
    const float* w  = Vw + ((size_t)r * 384 + q * 96) * 64 + t;
    const float* xr = llm + l * 384 + q * 96;
    float acc = 0.f;
#pragma unroll 4
    for (int d = 0; d < 96; ++d) acc += xr[d] * w[(size_t)d * 64];
    __shared__ float red[256];
    red[tid] = acc;
    __syncthreads();
    if (q == 0) {
        acc = red[t] + red[64 + t] + red[128 + t] + red[192 + t] + Vb[r * 64 + t];
        float ss = acc * acc;
#pragma unroll
        for (int m = 1; m < 64; m <<= 1) ss += __shfl_xor(ss, m);
        float inv = 1.0f / fmaxf(sqrtf(ss), 1e-12f);
        vl[((size_t)r * 64 + t) * 64 + l] = acc * inv;   // [r][h][l]
    }
}

// ---------------- gate: logits, top-2, aux partials, DIRECT scatter ----------------
// Fuses the old prefix_kernel + scatter_kernel: per-block histogram -> one
// global atomicAdd per router for the base -> write ent/ewt into fixed
// per-router segments (base r*CAP). Entry order within a segment is
// irrelevant to the gemm. Removes rinfo/wbuf globals entirely.
__global__ __launch_bounds__(256) void gate_kernel(
    const float* __restrict__ eh, const float* __restrict__ sr,
    const float* __restrict__ gw, const float* __restrict__ gb,
    int* __restrict__ ent, float* __restrict__ ewt,
    float* __restrict__ aux, int* __restrict__ cnt, int N)
{
    __shared__ int lcnt[8], lbase[8], lcur[8];
    __shared__ int   s_r01[32];
    __shared__ float s_w0[32], s_w1[32];
    int tid = threadIdx.x;
    if (tid < 8) { lcnt[tid] = 0; lcur[tid] = 0; }
    __syncthreads();
    int wave = tid >> 6, lane = tid & 63;
    int wgid = blockIdx.x * 4 + wave;
    float gbr[8];
#pragma unroll
    for (int r = 0; r < 8; ++r) gbr[r] = gb[r];
    float aux_acc = 0.f;

    for (int rr = 0; rr < 8; ++rr) {
        int row = wgid * 8 + rr;
        const float4* pa = (const float4*)(eh + (size_t)row * 384);
        const float4* pb = (const float4*)(sr + (size_t)row * 384);
        float4 xv0 = pa[lane];
        const float4* p1 = (lane < 32) ? (pa + 64 + lane) : (pb + (lane - 32));
        float4 xv1 = *p1;
        float4 xv2 = pb[lane + 32];

        float lg[8];
#pragma unroll
        for (int r = 0; r < 8; ++r) lg[r] = 0.f;
        {
            const float* g0 = gw + (size_t)lane * 32;
            const float* g1 = gw + (size_t)(lane + 64) * 32;
            const float* g2 = gw + (size_t)(lane + 128) * 32;
            float xd;
#pragma unroll
            for (int dd = 0; dd < 4; ++dd) {
                xd = (dd == 0) ? xv0.x : (dd == 1) ? xv0.y : (dd == 2) ? xv0.z : xv0.w;
#pragma unroll
                for (int r = 0; r < 8; ++r) lg[r] += xd * g0[dd * 8 + r];
            }
#pragma unroll
            for (int dd = 0; dd < 4; ++dd) {
                xd = (dd == 0) ? xv1.x : (dd == 1) ? xv1.y : (dd == 2) ? xv1.z : xv1.w;
#pragma unroll
                for (int r = 0; r < 8; ++r) lg[r] += xd * g1[dd * 8 + r];
            }
#pragma unroll
            for (int dd = 0; dd < 4; ++dd) {
                xd = (dd == 0) ? xv2.x : (dd == 1) ? xv2.y : (dd == 2) ? xv2.z : xv2.w;
#pragma unroll
                for (int r = 0; r < 8; ++r) lg[r] += xd * g2[dd * 8 + r];
            }
        }
#pragma unroll
        for (int m = 1; m < 64; m <<= 1) {
#pragma unroll
            for (int r = 0; r < 8; ++r) lg[r] += __shfl_xor(lg[r], m);
        }
#pragma unroll
        for (int r = 0; r < 8; ++r) lg[r] += gbr[r];

        float mx = lg[0];
#pragma unroll
        for (int r = 1; r < 8; ++r) mx = fmaxf(mx, lg[r]);
        float e8[8], se = 0.f;
#pragma unroll
        for (int r = 0; r < 8; ++r) { e8[r] = expf(lg[r] - mx); se += e8[r]; }

        int r0 = 0; float v0 = lg[0];
#pragma unroll
        for (int r = 1; r < 8; ++r) if (lg[r] > v0) { v0 = lg[r]; r0 = r; }
        int r1 = (r0 == 0) ? 1 : 0; float v1 = lg[r1];
#pragma unroll
        for (int r = 0; r < 8; ++r) if (r != r1 && r != r0 && lg[r] > v1) { v1 = lg[r]; r1 = r; }
        float z = expf(v1 - v0);
        float w0 = 1.f / (1.f + z), w1 = z / (1.f + z);

        if (lane == 0) {
            s_r01[wave * 8 + rr] = r0 | (r1 << 4);
            s_w0[wave * 8 + rr] = w0;
            s_w1[wave * 8 + rr] = w1;
            atomicAdd(&lcnt[r0], 1);
            atomicAdd(&lcnt[r1], 1);
        }
#pragma unroll
        for (int r2 = 0; r2 < 8; ++r2) {
            if (lane == r2) aux_acc += e8[r2] / se;
            if (lane - 8 == r2) aux_acc += (r2 == r0 || r2 == r1) ? 1.f : 0.f;
        }
    }
    if (lane < 16) atomicAdd(aux + ((size_t)(wgid & (AUX_SLOTS - 1)) * 16) + lane, aux_acc);
    __syncthreads();
    if (tid < 8) lbase[tid] = atomicAdd(&cnt[tid], lcnt[tid]);
    __syncthreads();
    if (tid < 32) {   // one thread per row of this block: write both entries
        int ri = s_r01[tid];
        int row = blockIdx.x * 32 + tid;
        int r0 = ri & 15, r1 = (ri >> 4) & 15;
        int p0 = lbase[r0] + atomicAdd(&lcur[r0], 1);
        ent[r0 * CAP + p0] = row << 1;       ewt[r0 * CAP + p0] = s_w0[tid];
        int p1 = lbase[r1] + atomicAdd(&lcur[r1], 1);
        ent[r1 * CAP + p1] = (row << 1) | 1; ewt[r1 * CAP + p1] = s_w1[tid];
    }
}

// ---------------- fused projection GEMM + l2norm + scores + softmax ----------------
// EXACT round-2 structure (283us gemm, proven best across rounds 0-8):
// tile 128 rows x 64 h, 256 threads, 4x8 micro-tile, K-chunk 32, sync staging,
// launch_bounds(256,3) (VGPR 80, no spill), LDS 25.6KB -> high residency.
// Only change: ent segments at constant base r*CAP (no off[] array).
__global__ __launch_bounds__(256, 3) void gemm_kernel(
    const float* __restrict__ eh, const float* __restrict__ sr,
    const float* __restrict__ Uw, const float* __restrict__ Ub,
    const float* __restrict__ vl, const int* __restrict__ ent,
    const float* __restrict__ ewt, const int* __restrict__ cnt,
    float* __restrict__ probs)
{
    int r = blockIdx.y;
    int count = cnt[r]; if (count > CAP) count = CAP;
    int tile = blockIdx.x;
    if (tile * 128 >= count) return;
    int base = r * CAP + tile * 128;

    __shared__ float xs[128 * 32];   // 16 KB, f4-swizzled [row][k4 ^ ((row>>2)&7)]
    __shared__ float us[32 * 64];    // 8 KB, U chunk [k][h]
    __shared__ int   sent[128];
    __shared__ float swt[128];

    int tid = threadIdx.x;
    int tx = tid & 7, ty = tid >> 3;   // ty 0..31, rows 4ty..4ty+3; h 8tx..8tx+7
    float4* xs4 = (float4*)xs;
    float4* us4 = (float4*)us;

    if (tid < 128) {
        bool act = (tile * 128 + tid) < count;
        sent[tid] = act ? ent[base + tid] : -1;
        swt[tid]  = act ? ewt[base + tid] : 0.f;
    }
    __syncthreads();

    // cache this thread's staging row ids (rloc = ty + 32p)
    int rowp[4];
#pragma unroll
    for (int p = 0; p < 4; ++p) {
        int e = sent[ty + 32 * p];
        rowp[p] = (e < 0) ? 0 : (e >> 1);
    }

    float acc[4][8];
#pragma unroll
    for (int i = 0; i < 4; ++i)
#pragma unroll
        for (int j = 0; j < 8; ++j) acc[i][j] = 0.f;

    for (int c = 0; c < 24; ++c) {
        const float* xsrc = (c < 12) ? eh : sr;
        int dd0 = ((c < 12) ? c : c - 12) * 32;
        {   // stage x: 4 f4 per thread, 128B contiguous per row
#pragma unroll
            for (int p = 0; p < 4; ++p) {
                int rloc = ty + 32 * p;
                float4 v = ((const float4*)(xsrc + (size_t)rowp[p] * 384 + dd0))[tx];
                xs4[rloc * 8 + (tx ^ ((rloc >> 2) & 7))] = v;
            }
        }
        {   // stage U chunk [32k][64h], linear
            const float4* pu = (const float4*)(Uw + ((size_t)r * 768 + (size_t)c * 32) * 64);
            us4[tid] = pu[tid];
            us4[tid + 256] = pu[tid + 256];
        }
        __syncthreads();
#pragma unroll
        for (int k4 = 0; k4 < 8; ++k4) {
            float4 a[4];
#pragma unroll
            for (int i = 0; i < 4; ++i)
                a[i] = xs4[(4 * ty + i) * 8 + (k4 ^ (ty & 7))];
#pragma unroll
            for (int j = 0; j < 4; ++j) {
                float4 b0 = us4[(k4 * 4 + j) * 16 + tx * 2];
                float4 b1 = us4[(k4 * 4 + j) * 16 + tx * 2 + 1];
#pragma unroll
                for (int i = 0; i < 4; ++i) {
                    float av = (j == 0) ? a[i].x : (j == 1) ? a[i].y : (j == 2) ? a[i].z : a[i].w;
                    acc[i][0] += av * b0.x; acc[i][1] += av * b0.y;
                    acc[i][2] += av * b0.z; acc[i][3] += av * b0.w;
                    acc[i][4] += av * b1.x; acc[i][5] += av * b1.y;
                    acc[i][6] += av * b1.z; acc[i][7] += av * b1.w;
                }
            }
        }
        __syncthreads();
    }

    // bias + l2-normalize rows (partial over tx, xor-shfl 1,2,4)
    float ub[8];
#pragma unroll
    for (int j = 0; j < 8; ++j) ub[j] = Ub[r * 64 + 8 * tx + j];
#pragma unroll
    for (int i = 0; i < 4; ++i) {
        float ss = 0.f;
#pragma unroll
        for (int j = 0; j < 8; ++j) { acc[i][j] += ub[j]; ss += acc[i][j] * acc[i][j]; }
#pragma unroll
        for (int m = 1; m <= 4; m <<= 1) ss += __shfl_xor(ss, m);
        float inv = 1.0f / fmaxf(sqrtf(ss), 1e-12f);
#pragma unroll
        for (int j = 0; j < 8; ++j) acc[i][j] *= inv;
    }

    // stage vl[r] (16 KB) into xs, swizzled [h][l4 ^ ((h>>3)&7)]
    {
        const float4* pv = (const float4*)(vl + (size_t)r * 4096);
#pragma unroll
        for (int p = 0; p < 4; ++p) {
            int idx = tid + p * 256;
            int h = idx >> 4, l4 = idx & 15;
            xs4[h * 16 + (l4 ^ ((h >> 3) & 7))] = pv[idx];
        }
    }
    __syncthreads();

    // scores + softmax + store, in two 2-row halves (register pressure)
#pragma unroll
    for (int ih = 0; ih < 4; ih += 2) {
        float sc[2][8];
        for (int lc = 0; lc < 8; ++lc) {
            float part[2][8];
#pragma unroll
            for (int i = 0; i < 2; ++i)
#pragma unroll
                for (int j = 0; j < 8; ++j) part[i][j] = 0.f;
#pragma unroll
            for (int j = 0; j < 8; ++j) {
                int h = 8 * tx + j;
                float4 v0 = xs4[h * 16 + ((2 * lc) ^ tx)];
                float4 v1 = xs4[h * 16 + ((2 * lc + 1) ^ tx)];
#pragma unroll
                for (int i = 0; i < 2; ++i) {
                    float uv = acc[ih + i][j];
                    part[i][0] += uv * v0.x; part[i][1] += uv * v0.y;
                    part[i][2] += uv * v0.z; part[i][3] += uv * v0.w;
                    part[i][4] += uv * v1.x; part[i][5] += uv * v1.y;
                    part[i][6] += uv * v1.z; part[i][7] += uv * v1.w;
                }
            }
#pragma unroll
            for (int m = 1; m <= 4; m <<= 1)
#pragma unroll
                for (int i = 0; i < 2; ++i)
#pragma unroll
                    for (int j = 0; j < 8; ++j) part[i][j] += __shfl_xor(part[i][j], m);
            if (tx == lc) {
#pragma unroll
                for (int i = 0; i < 2; ++i)
#pragma unroll
                    for (int j = 0; j < 8; ++j) sc[i][j] = part[i][j];
            }
        }
#pragma unroll
        for (int i = 0; i < 2; ++i) {
            float mx = sc[i][0];
#pragma unroll
            for (int j = 1; j < 8; ++j) mx = fmaxf(mx, sc[i][j]);
#pragma unroll
            for (int m = 1; m <= 4; m <<= 1) mx = fmaxf(mx, __shfl_xor(mx, m));
            float e[8], ssum = 0.f;
#pragma unroll
            for (int j = 0; j < 8; ++j) { e[j] = expf(sc[i][j] - mx); ssum += e[j]; }
#pragma unroll
            for (int m = 1; m <= 4; m <<= 1) ssum += __shfl_xor(ssum, m);
            int rloc = 4 * ty + ih + i;
            int ei = sent[rloc];
            if (ei >= 0) {
                float w = swt[rloc];
                float4 o0, o1;
                o0.x = (e[0] / ssum) * w; o0.y = (e[1] / ssum) * w;
                o0.z = (e[2] / ssum) * w; o0.w = (e[3] / ssum) * w;
                o1.x = (e[4] / ssum) * w; o1.y = (e[5] / ssum) * w;
                o1.z = (e[6] / ssum) * w; o1.w = (e[7] / ssum) * w;
                size_t bo = (size_t)(ei >> 1) * 128 + (size_t)(ei & 1) * 64 + 8 * tx;
                *(float4*)(probs + bo) = o0;
                *(float4*)(probs + bo + 4) = o1;
            }
        }
    }
}

// ---------------- combine: p = k0+k1, sequential cumsum, select, log ----------------
__global__ __launch_bounds__(256) void combine_kernel(
    const float* __restrict__ probs, const float* __restrict__ rnd,
    float* __restrict__ out, int N)
{
    int w = threadIdx.x >> 6, lane = threadIdx.x & 63;
    int n = blockIdx.x * 4 + w;
    float p = probs[(size_t)n * 128 + lane] + probs[(size_t)n * 128 + 64 + lane];
    float rn = rnd[n];
    float c = 0.f; int sel = 0; bool found = false;
    for (int l = 0; l < 64; ++l) {
        float v = __shfl(p, l);
        c += v;
        if (!found && c > rn) { sel = l; found = true; }
    }
    float pv = __shfl(p, sel);
    if (lane == 0) {
        out[n] = (float)sel;
        out[N + n] = logf(pv);
    }
}

__global__ __launch_bounds__(256) void aux_kernel(const float* __restrict__ aux,
                                                  float* __restrict__ out, int N) {
    __shared__ float red[256];
    int tid = threadIdx.x;
    int j = tid & 15, s0 = tid >> 4;
    float acc = 0.f;
    for (int s = s0; s < AUX_SLOTS; s += 16) acc += aux[s * 16 + j];
    red[tid] = acc;
    __syncthreads();
    if (tid < 16) {
        float a = 0.f;
        for (int g = 0; g < 16; ++g) a += red[g * 16 + tid];
        red[tid] = a;
    }
    __syncthreads();
    if (tid == 0) {
        float invN = 1.f / (float)N;
        float t = 0.f;
        for (int r2 = 0; r2 < 8; ++r2) t += (red[r2] * invN) * (red[8 + r2] * invN);
        out[2 * N] = 8.0f * 0.05f * t;
    }
}

extern "C" void kernel_launch(void* const* d_in, const int* in_sizes, int n_in,
                              void* d_out, int out_size, void* d_ws, size_t ws_size,
                              hipStream_t stream) {
    const float* eh  = (const float*)d_in[0];
    const float* sr  = (const float*)d_in[1];
    const float* llm = (const float*)d_in[2];
    const float* rnd = (const float*)d_in[3];
    const float* gw  = (const float*)d_in[4];
    const float* gb  = (const float*)d_in[5];
    const float* Uw  = (const float*)d_in[6];
    const float* Ub  = (const float*)d_in[7];
    const float* Vw  = (const float*)d_in[8];
    const float* Vb  = (const float*)d_in[9];
    int N = in_sizes[0] / 384;

    float* vl    = (float*)d_ws;              // 32768 f
    float* aux   = vl + 32768;                // 16384 f
    int*   cnt   = (int*)(aux + 16384);       // 8 i
    int*   ent   = cnt + 8;                   // 8*CAP i
    float* ewt   = (float*)(ent + 8 * CAP);   // 8*CAP f
    float* probs = ewt + 8 * CAP;             // N*128 f

    hipMemsetAsync(aux, 0, 16384 * sizeof(float) + 8 * sizeof(int), stream);
    vl_kernel<<<512, 256, 0, stream>>>(llm, Vw, Vb, vl);
    gate_kernel<<<N / 32, 256, 0, stream>>>(eh, sr, gw, gb, ent, ewt, aux, cnt, N);
    gemm_kernel<<<dim3(CAP / 128, 8), 256, 0, stream>>>(eh, sr, Uw, Ub, vl, ent, ewt,
                                                        cnt, probs);
    combine_kernel<<<N / 4, 256, 0, stream>>>(probs, rnd, (float*)d_out, N);
    aux_kernel<<<1, 256, 0, stream>>>(aux, (float*)d_out, N);
}